// Round 2
// baseline (1041.622 us; speedup 1.0000x reference)
//
#include <hip/hip_runtime.h>

#define INF_F 1e20f
#define B_ 16
#define Q_ 64
#define M_ 512
#define F_ 16
#define D_ 512

// Fused: QK^T attention GEMM + masks + f-max  -> att_qm
//        + softmax(ctx_mask)-weighted f-sum of in_memory  -> in_mem_base
//        + plain f-sum of out_memory                      -> out_mem_sum
// Block: 64 q x 256 rows (16 m x 16 f) of one b, 256 threads, 8x8 register tile.
__global__ __launch_bounds__(256) void k_att_fused(
    const float* __restrict__ query, const float* __restrict__ in_mem,
    const float* __restrict__ out_mem_in,
    const float* __restrict__ ctx_mask, const float* __restrict__ query_mask,
    float* __restrict__ att_qm, float* __restrict__ in_mem_base,
    float* __restrict__ out_mem_sum)
{
    __shared__ float4 As4[64 * 8];     // 8 KB   query tile   [q][d4 ^ (q&7)]
    __shared__ float4 Bs4[256 * 8];    // 32 KB  in_mem tile  [r][d4 ^ (r&7)]
    __shared__ float4 Os4[256 * 8];    // 32 KB  out_mem tile (same layout)
    __shared__ float  wgt[16][16];     // 1 KB   per-m softmax-over-f weights

    int b  = blockIdx.y;
    int mc = blockIdx.x;               // m-chunk: 16 m's
    int t  = threadIdx.x;
    int ty = t >> 5;                   // 0..7 -> q group
    int tx = t & 31;                   // 0..31 -> r lane

    // per-m softmax(mask) weights over f (matches reference kb_feature_att)
    if (t < 16) {
        const float* cm = ctx_mask + ((size_t)b*M_ + mc*16 + t)*F_;
        float wv[F_]; float mx = -INF_F;
        #pragma unroll
        for (int f = 0; f < F_; ++f) {
            float c = cm[f];
            float v = c - (1.0f - c) * INF_F;
            wv[f] = v; mx = fmaxf(mx, v);
        }
        float s = 0.f;
        #pragma unroll
        for (int f = 0; f < F_; ++f) { wv[f] = __expf(wv[f] - mx); s += wv[f]; }
        float inv = 1.0f / s;
        #pragma unroll
        for (int f = 0; f < F_; ++f) wgt[t][f] = wv[f] * inv;
    }

    const float4* q4 = (const float4*)query;       // [B*Q][128]
    const float4* m4 = (const float4*)in_mem;      // [B*M*F][128]
    const float4* o4 = (const float4*)out_mem_in;  // [B*M*F][128]
    size_t qbase = (size_t)b * Q_ * 128;
    size_t mbase = ((size_t)b * M_ + (size_t)mc * 16) * F_ * 128;

    float acc[8][8];
    #pragma unroll
    for (int i = 0; i < 8; ++i)
        #pragma unroll
        for (int j = 0; j < 8; ++j) acc[i][j] = 0.f;

    for (int kc = 0; kc < 16; ++kc) {
        int k4 = kc * 8;
        #pragma unroll
        for (int i = 0; i < 2; ++i) {              // stage A: 512 float4
            int idx = t + i * 256;
            int row = idx >> 3, c = idx & 7;
            As4[row*8 + (c ^ (row & 7))] = q4[qbase + (size_t)row*128 + k4 + c];
        }
        #pragma unroll
        for (int i = 0; i < 8; ++i) {              // stage B + OUT: 2048 float4 each
            int idx = t + i * 256;
            int row = idx >> 3, c = idx & 7;
            int    sl = row*8 + (c ^ (row & 7));
            size_t ga = mbase + (size_t)row*128 + k4 + c;
            Bs4[sl] = m4[ga];
            Os4[sl] = o4[ga];
        }
        __syncthreads();

        // GEMM: 8x8 per-thread tile over this d-chunk
        #pragma unroll
        for (int d4 = 0; d4 < 8; ++d4) {
            float4 av[8], bv[8];
            #pragma unroll
            for (int i = 0; i < 8; ++i) av[i] = As4[(ty*8 + i)*8 + (d4 ^ i)];
            #pragma unroll
            for (int j = 0; j < 8; ++j) bv[j] = Bs4[(j*32 + tx)*8 + (d4 ^ (tx & 7))];
            #pragma unroll
            for (int i = 0; i < 8; ++i)
                #pragma unroll
                for (int j = 0; j < 8; ++j) {
                    acc[i][j] += av[i].x * bv[j].x;
                    acc[i][j] += av[i].y * bv[j].y;
                    acc[i][j] += av[i].z * bv[j].z;
                    acc[i][j] += av[i].w * bv[j].w;
                }
        }

        // f-reductions from the staged tiles (complete per d-chunk):
        // threads 0..127: weighted in_mem -> in_mem_base; 128..255: out_mem sum.
        if (t < 128) {
            int m = t >> 3, c = t & 7;
            float4 s4 = make_float4(0,0,0,0);
            #pragma unroll
            for (int f = 0; f < F_; ++f) {
                int row = m*16 + f;                 // row&7 == f&7
                float4 v = Bs4[row*8 + (c ^ (f & 7))];
                float w = wgt[m][f];
                s4.x += w*v.x; s4.y += w*v.y; s4.z += w*v.z; s4.w += w*v.w;
            }
            ((float4*)in_mem_base)[((size_t)b*M_ + mc*16 + m)*128 + k4 + c] = s4;
        } else {
            int tt = t - 128;
            int m = tt >> 3, c = tt & 7;
            float4 s4 = make_float4(0,0,0,0);
            #pragma unroll
            for (int f = 0; f < F_; ++f) {
                int row = m*16 + f;
                float4 v = Os4[row*8 + (c ^ (f & 7))];
                s4.x += v.x; s4.y += v.y; s4.z += v.z; s4.w += v.w;
            }
            ((float4*)out_mem_sum)[((size_t)b*M_ + mc*16 + m)*128 + k4 + c] = s4;
        }
        __syncthreads();
    }

    // masks + max over f (16-lane groups), write att_qm
    int m_base = mc * 16;
    int f = tx & 15;
    #pragma unroll
    for (int j = 0; j < 8; ++j) {
        int m_loc = 2*j + (tx >> 4);
        float cmv = ctx_mask[((size_t)b*M_ + m_base + m_loc)*F_ + f];
        #pragma unroll
        for (int i = 0; i < 8; ++i) {
            int q = ty*8 + i;
            float qmv = query_mask[b*Q_ + q];
            float v = acc[i][j];
            v = cmv*v - (1.0f - cmv) * INF_F;
            v = qmv*v - (1.0f - qmv) * INF_F;
            #pragma unroll
            for (int s = 1; s < 16; s <<= 1) v = fmaxf(v, __shfl_xor(v, s, 64));
            if (f == 0)
                att_qm[((size_t)b*Q_ + q)*M_ + m_base + m_loc] = v;
        }
    }
}

// probs[b,q,:] = softmax over M
__global__ __launch_bounds__(256) void k_softmax_m(
    const float* __restrict__ att, float* __restrict__ probs)
{
    int bq = blockIdx.x; int t = threadIdx.x;
    const float* row = att + (size_t)bq * M_;
    float v0 = row[t], v1 = row[t + 256];
    float mx = fmaxf(v0, v1);
    __shared__ float red[4];
    #pragma unroll
    for (int s = 1; s < 64; s <<= 1) mx = fmaxf(mx, __shfl_xor(mx, s, 64));
    if ((t & 63) == 0) red[t >> 6] = mx;
    __syncthreads();
    mx = fmaxf(fmaxf(red[0], red[1]), fmaxf(red[2], red[3]));
    float e0 = __expf(v0 - mx), e1 = __expf(v1 - mx);
    float sm = e0 + e1;
    __syncthreads();
    #pragma unroll
    for (int s = 1; s < 64; s <<= 1) sm += __shfl_xor(sm, s, 64);
    if ((t & 63) == 0) red[t >> 6] = sm;
    __syncthreads();
    sm = (red[0] + red[1]) + (red[2] + red[3]);
    float inv = 1.0f / sm;
    probs[(size_t)bq*M_ + t]       = e0 * inv;
    probs[(size_t)bq*M_ + t + 256] = e1 * inv;
}

// p2t[b,m,q] = softmax over Q of att_qm[b,:,m] (stored transposed)
__global__ __launch_bounds__(256) void k_softmax_q(
    const float* __restrict__ att, float* __restrict__ p2t)
{
    __shared__ float T[64][65];
    __shared__ float cinv[64];
    int b = blockIdx.y, mc = blockIdx.x;
    int t = threadIdx.x;
    #pragma unroll
    for (int i = 0; i < 16; ++i) {
        int idx = t + i * 256;
        int q = idx >> 6, j = idx & 63;
        T[q][j] = att[((size_t)b*Q_ + q)*M_ + mc*64 + j];
    }
    __syncthreads();
    if (t < 64) {
        float mx = -INF_F;
        #pragma unroll
        for (int q = 0; q < 64; ++q) mx = fmaxf(mx, T[q][t]);
        float s = 0.f;
        #pragma unroll
        for (int q = 0; q < 64; ++q) { float e = __expf(T[q][t] - mx); T[q][t] = e; s += e; }
        cinv[t] = 1.0f / s;
    }
    __syncthreads();
    #pragma unroll
    for (int i = 0; i < 16; ++i) {
        int idx = t + i * 256;
        int j = idx >> 6, q = idx & 63;
        p2t[((size_t)b*M_ + mc*64 + j)*Q_ + q] = T[q][j] * cinv[j];
    }
}

// new_query = query + probs @ out_mem
__global__ __launch_bounds__(128) void k_new_query(
    const float* __restrict__ query, const float* __restrict__ probs,
    const float* __restrict__ out_mem, float* __restrict__ new_q)
{
    __shared__ float P[8][512];
    int b = blockIdx.y, q0 = blockIdx.x * 8;
    int t = threadIdx.x;
    #pragma unroll
    for (int i = 0; i < 32; ++i) {
        int idx = t + i * 128;
        P[idx >> 9][idx & 511] = probs[((size_t)b*Q_ + q0 + (idx >> 9))*M_ + (idx & 511)];
    }
    __syncthreads();
    const float4* q4 = (const float4*)query;
    const float4* o4 = (const float4*)out_mem;
    float4 acc[8];
    #pragma unroll
    for (int qi = 0; qi < 8; ++qi) acc[qi] = q4[((size_t)b*Q_ + q0 + qi)*128 + t];
    for (int m = 0; m < M_; ++m) {
        float4 ov = o4[((size_t)b*M_ + m)*128 + t];
        #pragma unroll
        for (int qi = 0; qi < 8; ++qi) {
            float p = P[qi][m];
            acc[qi].x += p*ov.x; acc[qi].y += p*ov.y; acc[qi].z += p*ov.z; acc[qi].w += p*ov.w;
        }
    }
    float4* nq4 = (float4*)new_q;
    #pragma unroll
    for (int qi = 0; qi < 8; ++qi) nq4[((size_t)b*Q_ + q0 + qi)*128 + t] = acc[qi];
}

// in_mem[b,m,:] += sum_q p2t[b,m,q] * new_query[b,q,:]
__global__ __launch_bounds__(128) void k_in_mem(
    const float* __restrict__ p2t, const float* __restrict__ new_q,
    float* __restrict__ in_mem_out)
{
    __shared__ float P[8][64];
    int b = blockIdx.y, m0 = blockIdx.x * 8;
    int t = threadIdx.x;
    #pragma unroll
    for (int i = 0; i < 4; ++i) {
        int idx = t + i * 128;
        P[idx >> 6][idx & 63] = p2t[((size_t)b*M_ + m0 + (idx >> 6))*Q_ + (idx & 63)];
    }
    __syncthreads();
    const float4* n4 = (const float4*)new_q;
    float4* im4 = (float4*)in_mem_out;
    float4 acc[8];
    #pragma unroll
    for (int mi = 0; mi < 8; ++mi) acc[mi] = im4[((size_t)b*M_ + m0 + mi)*128 + t];
    for (int q = 0; q < Q_; ++q) {
        float4 nv = n4[((size_t)b*Q_ + q)*128 + t];
        #pragma unroll
        for (int mi = 0; mi < 8; ++mi) {
            float p = P[mi][q];
            acc[mi].x += p*nv.x; acc[mi].y += p*nv.y; acc[mi].z += p*nv.z; acc[mi].w += p*nv.w;
        }
    }
    #pragma unroll
    for (int mi = 0; mi < 8; ++mi) im4[((size_t)b*M_ + m0 + mi)*128 + t] = acc[mi];
}

extern "C" void kernel_launch(void* const* d_in, const int* in_sizes, int n_in,
                              void* d_out, int out_size, void* d_ws, size_t ws_size,
                              hipStream_t stream)
{
    const float* query      = (const float*)d_in[0];
    const float* in_mem     = (const float*)d_in[1];
    const float* out_mem    = (const float*)d_in[2];
    const float* ctx_mask   = (const float*)d_in[3];
    const float* query_mask = (const float*)d_in[4];

    float* out = (float*)d_out;
    float* new_q      = out;                             // B*Q*D
    float* in_mem_out = out + (size_t)B_*Q_*D_;          // B*M*D
    float* out_mem_o  = in_mem_out + (size_t)B_*M_*D_;   // B*M*D

    float* ws     = (float*)d_ws;
    float* att_qm = ws;                                  // B*Q*M
    float* probs  = att_qm + (size_t)B_*Q_*M_;           // B*Q*M
    float* p2t    = probs  + (size_t)B_*Q_*M_;           // B*M*Q

    hipLaunchKernelGGL(k_att_fused, dim3(32, B_), dim3(256), 0, stream,
                       query, in_mem, out_mem, ctx_mask, query_mask,
                       att_qm, in_mem_out, out_mem_o);
    hipLaunchKernelGGL(k_softmax_m, dim3(B_*Q_), dim3(256), 0, stream, att_qm, probs);
    hipLaunchKernelGGL(k_softmax_q, dim3(8, B_), dim3(256), 0, stream, att_qm, p2t);
    hipLaunchKernelGGL(k_new_query, dim3(8, B_), dim3(128), 0, stream,
                       query, probs, out_mem_o, new_q);
    hipLaunchKernelGGL(k_in_mem, dim3(64, B_), dim3(128), 0, stream,
                       p2t, new_q, in_mem_out);
}

// Round 3
// 268.629 us; speedup vs baseline: 3.8775x; 3.8775x over previous
//
#include <hip/hip_runtime.h>

#define INF_F 1e20f
#define B_ 16
#define Q_ 64
#define M_ 512
#define F_ 16
#define D_ 512

typedef __attribute__((ext_vector_type(8))) short short8v;
typedef __attribute__((ext_vector_type(4))) float f32x4;

// bf16 RNE high part (bits) of f; standard round-to-nearest-even truncation.
static __device__ __forceinline__ unsigned int bf16_hi_bits(float f) {
    unsigned int u = __float_as_uint(f);
    return (u + 0x7fffu + ((u >> 16) & 1u)) & 0xffff0000u;
}
static __device__ __forceinline__ float bits_to_f32(unsigned int hi) {
    return __uint_as_float(hi);
}
// pack two floats' bf16(RNE) into one uint (a in low 16, b in high 16)
static __device__ __forceinline__ unsigned int pk_bf16(float a, float b) {
    return (bf16_hi_bits(a) >> 16) | bf16_hi_bits(b);
}
static __device__ __forceinline__ float bf_lo(unsigned int u) {   // low 16 bits -> float
    return __uint_as_float(u << 16);
}
static __device__ __forceinline__ float bf_hi(unsigned int u) {   // high 16 bits -> float
    return __uint_as_float(u & 0xffff0000u);
}

// K2: fused attention GEMM (bf16 hi/lo split MFMA) + masks + f-max -> att_qm
//     + softmax(ctx_mask)-weighted f-sum of in_memory -> in_mem_base
// Block: 256 thr = 4 waves. Covers all 64 q x 8 m (128 rows) of one batch.
// Each wave: 2 m-tiles x 4 q-tiles of 16x16 via mfma_f32_16x16x32_bf16.
__global__ __launch_bounds__(256) void k_att_mfma(
    const float* __restrict__ query, const float* __restrict__ in_mem,
    const float* __restrict__ ctx_mask, const float* __restrict__ query_mask,
    float* __restrict__ att_qm, float* __restrict__ in_mem_base)
{
    // padded rows: 32 bf16 (64B) + 16B pad = 80B = 40 shorts
    __shared__ __align__(16) short Qh[64 * 40];
    __shared__ __align__(16) short Ql[64 * 40];
    __shared__ __align__(16) short Mh[128 * 40];
    __shared__ __align__(16) short Ml[128 * 40];
    __shared__ float wgt[8][16];

    const int b  = blockIdx.y;
    const int m0 = blockIdx.x * 8;          // 8 m per block
    const int t  = threadIdx.x;
    const int w  = t >> 6;                  // wave 0..3
    const int lane = t & 63;
    const int lr = lane & 15;               // col index (f) / row-in-tile
    const int lg = lane >> 4;               // k-slot 0..3

    // softmax-over-f weights for the 8 m's (matches reference kb_feature_att)
    if (t < 8) {
        const float* cm = ctx_mask + ((size_t)b * M_ + m0 + t) * F_;
        float wv[F_]; float mx = -INF_F;
        #pragma unroll
        for (int f = 0; f < F_; ++f) {
            float c = cm[f];
            float v = c - (1.0f - c) * INF_F;
            wv[f] = v; mx = fmaxf(mx, v);
        }
        float s = 0.f;
        #pragma unroll
        for (int f = 0; f < F_; ++f) { wv[f] = __expf(wv[f] - mx); s += wv[f]; }
        float inv = 1.0f / s;
        #pragma unroll
        for (int f = 0; f < F_; ++f) wgt[t][f] = wv[f] * inv;
    }

    const float4* q4 = (const float4*)query;   // [B*Q][128]
    const float4* m4 = (const float4*)in_mem;  // [B*M*F][128]
    const size_t qbase = (size_t)b * Q_ * 128;
    const size_t mbase = ((size_t)b * M_ + m0) * F_ * 128;  // 128 contiguous rows

    f32x4 acc[2][4];
    #pragma unroll
    for (int i = 0; i < 2; ++i)
        #pragma unroll
        for (int j = 0; j < 4; ++j) acc[i][j] = (f32x4){0,0,0,0};

    // staging registers (prefetch)
    float4 qv[2], mv[4];
    {   // prologue: chunk 0 loads
        #pragma unroll
        for (int i = 0; i < 2; ++i) {
            int idx = t + i * 256; int row = idx >> 3, c = idx & 7;
            qv[i] = q4[qbase + (size_t)row * 128 + c];
        }
        #pragma unroll
        for (int i = 0; i < 4; ++i) {
            int idx = t + i * 256; int row = idx >> 3, c = idx & 7;
            mv[i] = m4[mbase + (size_t)row * 128 + c];
        }
    }

    for (int kc = 0; kc < 16; ++kc) {
        __syncthreads();    // previous chunk's LDS reads done (and wgt ready)
        // convert + write staged regs to LDS (hi/lo bf16)
        #pragma unroll
        for (int i = 0; i < 2; ++i) {
            int idx = t + i * 256; int row = idx >> 3, c = idx & 7;
            float4 v = qv[i];
            unsigned int hx = bf16_hi_bits(v.x), hy = bf16_hi_bits(v.y);
            unsigned int hz = bf16_hi_bits(v.z), hw = bf16_hi_bits(v.w);
            uint2 H; H.x = (hx >> 16) | hy; H.y = (hz >> 16) | hw;
            uint2 L; L.x = pk_bf16(v.x - bits_to_f32(hx), v.y - bits_to_f32(hy));
            L.y = pk_bf16(v.z - bits_to_f32(hz), v.w - bits_to_f32(hw));
            *(uint2*)&Qh[row * 40 + c * 4] = H;
            *(uint2*)&Ql[row * 40 + c * 4] = L;
        }
        #pragma unroll
        for (int i = 0; i < 4; ++i) {
            int idx = t + i * 256; int row = idx >> 3, c = idx & 7;
            float4 v = mv[i];
            unsigned int hx = bf16_hi_bits(v.x), hy = bf16_hi_bits(v.y);
            unsigned int hz = bf16_hi_bits(v.z), hw = bf16_hi_bits(v.w);
            uint2 H; H.x = (hx >> 16) | hy; H.y = (hz >> 16) | hw;
            uint2 L; L.x = pk_bf16(v.x - bits_to_f32(hx), v.y - bits_to_f32(hy));
            L.y = pk_bf16(v.z - bits_to_f32(hz), v.w - bits_to_f32(hw));
            *(uint2*)&Mh[row * 40 + c * 4] = H;
            *(uint2*)&Ml[row * 40 + c * 4] = L;
        }
        __syncthreads();    // staging visible

        // prefetch next chunk's global data (hides HBM latency under MFMA)
        if (kc < 15) {
            int k4 = (kc + 1) * 8;
            #pragma unroll
            for (int i = 0; i < 2; ++i) {
                int idx = t + i * 256; int row = idx >> 3, c = idx & 7;
                qv[i] = q4[qbase + (size_t)row * 128 + k4 + c];
            }
            #pragma unroll
            for (int i = 0; i < 4; ++i) {
                int idx = t + i * 256; int row = idx >> 3, c = idx & 7;
                mv[i] = m4[mbase + (size_t)row * 128 + k4 + c];
            }
        }

        // MFMA: per wave 2 m-tiles x 4 q-tiles, hi/lo split (3 mfma each)
        #pragma unroll
        for (int tm = 0; tm < 2; ++tm) {
            int r = (w * 2 + tm) * 16 + lr;
            short8v bh = *(const short8v*)&Mh[r * 40 + lg * 8];
            short8v bl = *(const short8v*)&Ml[r * 40 + lg * 8];
            #pragma unroll
            for (int tq = 0; tq < 4; ++tq) {
                int qr = tq * 16 + lr;
                short8v ah = *(const short8v*)&Qh[qr * 40 + lg * 8];
                short8v al = *(const short8v*)&Ql[qr * 40 + lg * 8];
                acc[tm][tq] = __builtin_amdgcn_mfma_f32_16x16x32_bf16(ah, bh, acc[tm][tq], 0, 0, 0);
                acc[tm][tq] = __builtin_amdgcn_mfma_f32_16x16x32_bf16(ah, bl, acc[tm][tq], 0, 0, 0);
                acc[tm][tq] = __builtin_amdgcn_mfma_f32_16x16x32_bf16(al, bh, acc[tm][tq], 0, 0, 0);
            }
        }

        // weighted f-sum -> in_mem_base for this d-chunk (thread 0..63 = wave 0)
        if (t < 64) {
            int ml = t >> 3, c = t & 7;
            float4 s = make_float4(0, 0, 0, 0);
            #pragma unroll
            for (int f = 0; f < F_; ++f) {
                int f2 = (f + 2 * ml) & 15;       // rotate to spread LDS banks
                int row = ml * 16 + f2;
                uint2 H = *(const uint2*)&Mh[row * 40 + c * 4];
                uint2 L = *(const uint2*)&Ml[row * 40 + c * 4];
                float wf = wgt[ml][f2];
                s.x += wf * (bf_lo(H.x) + bf_lo(L.x));
                s.y += wf * (bf_hi(H.x) + bf_hi(L.x));
                s.z += wf * (bf_lo(H.y) + bf_lo(L.y));
                s.w += wf * (bf_hi(H.y) + bf_hi(L.y));
            }
            ((float4*)in_mem_base)[((size_t)b * M_ + m0 + ml) * 128 + kc * 8 + c] = s;
        }
    }

    // masks + max over f (16-lane groups), write att_qm
    #pragma unroll
    for (int tm = 0; tm < 2; ++tm) {
        int m = m0 + w * 2 + tm;
        float cmv = ctx_mask[((size_t)b * M_ + m) * F_ + lr];
        #pragma unroll
        for (int tq = 0; tq < 4; ++tq) {
            #pragma unroll
            for (int rg = 0; rg < 4; ++rg) {
                int q = tq * 16 + lg * 4 + rg;
                float qmv = query_mask[b * Q_ + q];
                float v = acc[tm][tq][rg];
                v = cmv * v - (1.0f - cmv) * INF_F;
                v = qmv * v - (1.0f - qmv) * INF_F;
                #pragma unroll
                for (int s = 1; s < 16; s <<= 1) v = fmaxf(v, __shfl_xor(v, s, 64));
                if (lr == 0)
                    att_qm[((size_t)b * Q_ + q) * M_ + m] = v;
            }
        }
    }
}

// f-sum of out_memory -> out_mem_sum. 2 m per block, 16 loads in flight.
__global__ __launch_bounds__(256) void k_out_sum(
    const float* __restrict__ om, float* __restrict__ os)
{
    int bm = blockIdx.x * 2 + (threadIdx.x >> 7);
    int c  = threadIdx.x & 127;
    const float4* src = (const float4*)om + (size_t)bm * F_ * 128 + c;
    float4 a = make_float4(0, 0, 0, 0);
    #pragma unroll
    for (int f = 0; f < F_; ++f) {
        float4 v = src[(size_t)f * 128];
        a.x += v.x; a.y += v.y; a.z += v.z; a.w += v.w;
    }
    ((float4*)os)[(size_t)bm * 128 + c] = a;
}

// probs[b,q,:] = softmax over M
__global__ __launch_bounds__(256) void k_softmax_m(
    const float* __restrict__ att, float* __restrict__ probs)
{
    int bq = blockIdx.x; int t = threadIdx.x;
    const float* row = att + (size_t)bq * M_;
    float v0 = row[t], v1 = row[t + 256];
    float mx = fmaxf(v0, v1);
    __shared__ float red[4];
    #pragma unroll
    for (int s = 1; s < 64; s <<= 1) mx = fmaxf(mx, __shfl_xor(mx, s, 64));
    if ((t & 63) == 0) red[t >> 6] = mx;
    __syncthreads();
    mx = fmaxf(fmaxf(red[0], red[1]), fmaxf(red[2], red[3]));
    float e0 = __expf(v0 - mx), e1 = __expf(v1 - mx);
    float sm = e0 + e1;
    __syncthreads();
    #pragma unroll
    for (int s = 1; s < 64; s <<= 1) sm += __shfl_xor(sm, s, 64);
    if ((t & 63) == 0) red[t >> 6] = sm;
    __syncthreads();
    sm = (red[0] + red[1]) + (red[2] + red[3]);
    float inv = 1.0f / sm;
    probs[(size_t)bq*M_ + t]       = e0 * inv;
    probs[(size_t)bq*M_ + t + 256] = e1 * inv;
}

// p2t[b,m,q] = softmax over Q of att_qm[b,:,m] (stored transposed)
__global__ __launch_bounds__(256) void k_softmax_q(
    const float* __restrict__ att, float* __restrict__ p2t)
{
    __shared__ float T[64][65];
    __shared__ float cinv[64];
    int b = blockIdx.y, mc = blockIdx.x;
    int t = threadIdx.x;
    #pragma unroll
    for (int i = 0; i < 16; ++i) {
        int idx = t + i * 256;
        int q = idx >> 6, j = idx & 63;
        T[q][j] = att[((size_t)b*Q_ + q)*M_ + mc*64 + j];
    }
    __syncthreads();
    if (t < 64) {
        float mx = -INF_F;
        #pragma unroll
        for (int q = 0; q < 64; ++q) mx = fmaxf(mx, T[q][t]);
        float s = 0.f;
        #pragma unroll
        for (int q = 0; q < 64; ++q) { float e = __expf(T[q][t] - mx); T[q][t] = e; s += e; }
        cinv[t] = 1.0f / s;
    }
    __syncthreads();
    #pragma unroll
    for (int i = 0; i < 16; ++i) {
        int idx = t + i * 256;
        int j = idx >> 6, q = idx & 63;
        p2t[((size_t)b*M_ + mc*64 + j)*Q_ + q] = T[q][j] * cinv[j];
    }
}

// new_query = query + probs @ out_mem
__global__ __launch_bounds__(128) void k_new_query(
    const float* __restrict__ query, const float* __restrict__ probs,
    const float* __restrict__ out_mem, float* __restrict__ new_q)
{
    __shared__ float P[8][512];
    int b = blockIdx.y, q0 = blockIdx.x * 8;
    int t = threadIdx.x;
    #pragma unroll
    for (int i = 0; i < 32; ++i) {
        int idx = t + i * 128;
        P[idx >> 9][idx & 511] = probs[((size_t)b*Q_ + q0 + (idx >> 9))*M_ + (idx & 511)];
    }
    __syncthreads();
    const float4* q4 = (const float4*)query;
    const float4* o4 = (const float4*)out_mem;
    float4 acc[8];
    #pragma unroll
    for (int qi = 0; qi < 8; ++qi) acc[qi] = q4[((size_t)b*Q_ + q0 + qi)*128 + t];
    for (int m = 0; m < M_; ++m) {
        float4 ov = o4[((size_t)b*M_ + m)*128 + t];
        #pragma unroll
        for (int qi = 0; qi < 8; ++qi) {
            float p = P[qi][m];
            acc[qi].x += p*ov.x; acc[qi].y += p*ov.y; acc[qi].z += p*ov.z; acc[qi].w += p*ov.w;
        }
    }
    float4* nq4 = (float4*)new_q;
    #pragma unroll
    for (int qi = 0; qi < 8; ++qi) nq4[((size_t)b*Q_ + q0 + qi)*128 + t] = acc[qi];
}

// in_mem[b,m,:] += sum_q p2t[b,m,q] * new_query[b,q,:]
__global__ __launch_bounds__(128) void k_in_mem(
    const float* __restrict__ p2t, const float* __restrict__ new_q,
    float* __restrict__ in_mem_out)
{
    __shared__ float P[8][64];
    int b = blockIdx.y, m0 = blockIdx.x * 8;
    int t = threadIdx.x;
    #pragma unroll
    for (int i = 0; i < 4; ++i) {
        int idx = t + i * 128;
        P[idx >> 6][idx & 63] = p2t[((size_t)b*M_ + m0 + (idx >> 6))*Q_ + (idx & 63)];
    }
    __syncthreads();
    const float4* n4 = (const float4*)new_q;
    float4* im4 = (float4*)in_mem_out;
    float4 acc[8];
    #pragma unroll
    for (int mi = 0; mi < 8; ++mi) acc[mi] = im4[((size_t)b*M_ + m0 + mi)*128 + t];
    for (int q = 0; q < Q_; ++q) {
        float4 nv = n4[((size_t)b*Q_ + q)*128 + t];
        #pragma unroll
        for (int mi = 0; mi < 8; ++mi) {
            float p = P[mi][q];
            acc[mi].x += p*nv.x; acc[mi].y += p*nv.y; acc[mi].z += p*nv.z; acc[mi].w += p*nv.w;
        }
    }
    #pragma unroll
    for (int mi = 0; mi < 8; ++mi) im4[((size_t)b*M_ + m0 + mi)*128 + t] = acc[mi];
}

extern "C" void kernel_launch(void* const* d_in, const int* in_sizes, int n_in,
                              void* d_out, int out_size, void* d_ws, size_t ws_size,
                              hipStream_t stream)
{
    const float* query      = (const float*)d_in[0];
    const float* in_mem     = (const float*)d_in[1];
    const float* out_mem    = (const float*)d_in[2];
    const float* ctx_mask   = (const float*)d_in[3];
    const float* query_mask = (const float*)d_in[4];

    float* out = (float*)d_out;
    float* new_q      = out;                             // B*Q*D
    float* in_mem_out = out + (size_t)B_*Q_*D_;          // B*M*D
    float* out_mem_o  = in_mem_out + (size_t)B_*M_*D_;   // B*M*D

    float* ws     = (float*)d_ws;
    float* att_qm = ws;                                  // B*Q*M
    float* probs  = att_qm + (size_t)B_*Q_*M_;           // B*Q*M
    float* p2t    = probs  + (size_t)B_*Q_*M_;           // B*M*Q

    hipLaunchKernelGGL(k_att_mfma, dim3(M_/8, B_), dim3(256), 0, stream,
                       query, in_mem, ctx_mask, query_mask, att_qm, in_mem_out);
    hipLaunchKernelGGL(k_out_sum, dim3(B_*M_/2), dim3(256), 0, stream,
                       out_mem, out_mem_o);
    hipLaunchKernelGGL(k_softmax_m, dim3(B_*Q_), dim3(256), 0, stream, att_qm, probs);
    hipLaunchKernelGGL(k_softmax_q, dim3(8, B_), dim3(256), 0, stream, att_qm, p2t);
    hipLaunchKernelGGL(k_new_query, dim3(8, B_), dim3(128), 0, stream,
                       query, probs, out_mem_o, new_q);
    hipLaunchKernelGGL(k_in_mem, dim3(64, B_), dim3(128), 0, stream,
                       p2t, new_q, in_mem_out);
}

// Round 4
// 229.647 us; speedup vs baseline: 4.5357x; 1.1697x over previous
//
#include <hip/hip_runtime.h>

#define INF_F 1e20f
#define B_ 16
#define Q_ 64
#define M_ 512
#define F_ 16
#define D_ 512

typedef __attribute__((ext_vector_type(8))) short short8v;
typedef __attribute__((ext_vector_type(4))) float f32x4;

static __device__ __forceinline__ float bits_f(unsigned int u) { return __uint_as_float(u); }
static __device__ __forceinline__ float lo_f(unsigned int u) { return __uint_as_float(u << 16); }
static __device__ __forceinline__ float hi_f(unsigned int u) { return __uint_as_float(u & 0xffff0000u); }

// LDS tile: 64 rows x 32 bf16 (4 granules of 16B) + 16B pad -> pitch 40 shorts.
// Granule-XOR swizzle: phys_granule = granule ^ (row & 3).
static __device__ __forceinline__ int lds_off(int row, int gran) {
    return row * 40 + ((gran ^ (row & 3)) << 3);
}

// convert float4 -> truncated-hi bf16x4 + lo bf16x4, store swizzled (c = float4 col 0..7)
static __device__ __forceinline__ void conv_store(short* __restrict__ Hb, short* __restrict__ Lb,
                                                  int row, int c, float4 v) {
    unsigned ux = __float_as_uint(v.x), uy = __float_as_uint(v.y);
    unsigned uz = __float_as_uint(v.z), uw = __float_as_uint(v.w);
    unsigned hx = ux & 0xffff0000u, hy = uy & 0xffff0000u;
    unsigned hz = uz & 0xffff0000u, hw = uw & 0xffff0000u;
    float lx = v.x - bits_f(hx), ly = v.y - bits_f(hy);
    float lz = v.z - bits_f(hz), lw = v.w - bits_f(hw);
    uint2 H, L;
    H.x = (hx >> 16) | hy;
    H.y = (hz >> 16) | hw;
    L.x = (__float_as_uint(lx) >> 16) | (__float_as_uint(ly) & 0xffff0000u);
    L.y = (__float_as_uint(lz) >> 16) | (__float_as_uint(lw) & 0xffff0000u);
    int off = row * 40 + (((c >> 1) ^ (row & 3)) << 3) + ((c & 1) << 2);
    *(uint2*)&Hb[off] = H;
    *(uint2*)&Lb[off] = L;
}

// K1: fused attention GEMM (bf16 hi/lo split MFMA) + masks + f-max -> att_qm
//     + softmax(ctx_mask)-weighted f-sum of in_memory -> in_mem_base
// Block: 256 thr = 4 waves; 4 m (64 B-rows) x 64 q; double-buffered LDS, 1 barrier/kc.
__global__ __launch_bounds__(256) void k_att_mfma(
    const float* __restrict__ query, const float* __restrict__ in_mem,
    const float* __restrict__ ctx_mask, const float* __restrict__ query_mask,
    float* __restrict__ att_qm, float* __restrict__ in_mem_base)
{
    __shared__ __align__(16) short Qh[2][64 * 40];
    __shared__ __align__(16) short Ql[2][64 * 40];
    __shared__ __align__(16) short Mh[2][64 * 40];
    __shared__ __align__(16) short Ml[2][64 * 40];

    const int bid = blockIdx.x;
    const int b   = bid & 15;            // batch -> XCD pin (b%8) + query L2 reuse
    const int m0  = (bid >> 4) * 4;      // 4 m per block
    const int t   = threadIdx.x;
    const int w   = t >> 6;              // wave 0..3 -> m = m0 + w
    const int lane = t & 63;
    const int lr  = lane & 15;           // B-row within tile (= f)
    const int lg  = lane >> 4;           // k-granule 0..3
    const int c8  = lane & 7;            // f-sum: float4 col
    const int fg  = lane >> 3;           // f-sum: f group 0..7

    // per-lane softmax-over-f weights for m = m0 + w (all lanes of wave w same m)
    float w_lo, w_hi;
    {
        const float* cm = ctx_mask + ((size_t)b * M_ + m0 + w) * F_;
        float wv[F_]; float mx = -INF_F;
        #pragma unroll
        for (int f = 0; f < F_; ++f) {
            float cv = cm[f];
            float v = cv - (1.0f - cv) * INF_F;
            wv[f] = v; mx = fmaxf(mx, v);
        }
        float s = 0.f;
        #pragma unroll
        for (int f = 0; f < F_; ++f) { wv[f] = __expf(wv[f] - mx); s += wv[f]; }
        float inv = 1.0f / s;
        w_lo = wv[fg] * inv; w_hi = wv[fg + 8] * inv;
    }

    const float4* q4 = (const float4*)query;   // [B*Q][128]
    const float4* m4 = (const float4*)in_mem;  // [B*M*F][128]
    const size_t qbase = (size_t)b * Q_ * 128;
    const size_t mbase = ((size_t)b * M_ + m0) * F_ * 128;   // 64 contiguous rows
    const int srow0 = t >> 3, scol = t & 7;    // staging: items t and t+256
    const int srow1 = srow0 + 32;

    f32x4 acc[4];
    #pragma unroll
    for (int j = 0; j < 4; ++j) acc[j] = (f32x4){0, 0, 0, 0};

    float4 qA[2], mA[2], qB[2], mB[2];

#define LOAD_CHUNK(qd, md, kc) do { int k4 = (kc) * 8;                           \
        qd[0] = q4[qbase + (size_t)srow0 * 128 + k4 + scol];                     \
        qd[1] = q4[qbase + (size_t)srow1 * 128 + k4 + scol];                     \
        md[0] = m4[mbase + (size_t)srow0 * 128 + k4 + scol];                     \
        md[1] = m4[mbase + (size_t)srow1 * 128 + k4 + scol]; } while (0)

#define CONV_CHUNK(qd, md, bi) do {                                              \
        conv_store(Qh[bi], Ql[bi], srow0, scol, qd[0]);                          \
        conv_store(Qh[bi], Ql[bi], srow1, scol, qd[1]);                          \
        conv_store(Mh[bi], Ml[bi], srow0, scol, md[0]);                          \
        conv_store(Mh[bi], Ml[bi], srow1, scol, md[1]); } while (0)

#define MFMA_FSUM(bi, kc) do {                                                   \
        short8v bh = *(const short8v*)&Mh[bi][lds_off(w * 16 + lr, lg)];         \
        short8v bl = *(const short8v*)&Ml[bi][lds_off(w * 16 + lr, lg)];         \
        _Pragma("unroll")                                                        \
        for (int tq = 0; tq < 4; ++tq) {                                         \
            short8v ah = *(const short8v*)&Qh[bi][lds_off(tq * 16 + lr, lg)];    \
            short8v al = *(const short8v*)&Ql[bi][lds_off(tq * 16 + lr, lg)];    \
            acc[tq] = __builtin_amdgcn_mfma_f32_16x16x32_bf16(ah, bh, acc[tq], 0, 0, 0); \
            acc[tq] = __builtin_amdgcn_mfma_f32_16x16x32_bf16(ah, bl, acc[tq], 0, 0, 0); \
            acc[tq] = __builtin_amdgcn_mfma_f32_16x16x32_bf16(al, bh, acc[tq], 0, 0, 0); \
        }                                                                        \
        float4 s = make_float4(0, 0, 0, 0);                                      \
        {   int rr = w * 16 + fg;                                                \
            int off = rr * 40 + (((c8 >> 1) ^ (rr & 3)) << 3) + ((c8 & 1) << 2); \
            uint2 H = *(const uint2*)&Mh[bi][off];                               \
            uint2 L = *(const uint2*)&Ml[bi][off];                               \
            s.x += w_lo * (lo_f(H.x) + lo_f(L.x));                               \
            s.y += w_lo * (hi_f(H.x) + hi_f(L.x));                               \
            s.z += w_lo * (lo_f(H.y) + lo_f(L.y));                               \
            s.w += w_lo * (hi_f(H.y) + hi_f(L.y));                               \
        }                                                                        \
        {   int rr = w * 16 + fg + 8;                                            \
            int off = rr * 40 + (((c8 >> 1) ^ (rr & 3)) << 3) + ((c8 & 1) << 2); \
            uint2 H = *(const uint2*)&Mh[bi][off];                               \
            uint2 L = *(const uint2*)&Ml[bi][off];                               \
            s.x += w_hi * (lo_f(H.x) + lo_f(L.x));                               \
            s.y += w_hi * (hi_f(H.x) + hi_f(L.x));                               \
            s.z += w_hi * (lo_f(H.y) + lo_f(L.y));                               \
            s.w += w_hi * (hi_f(H.y) + hi_f(L.y));                               \
        }                                                                        \
        _Pragma("unroll")                                                        \
        for (int sh = 8; sh <= 32; sh <<= 1) {                                   \
            s.x += __shfl_xor(s.x, sh, 64); s.y += __shfl_xor(s.y, sh, 64);      \
            s.z += __shfl_xor(s.z, sh, 64); s.w += __shfl_xor(s.w, sh, 64);      \
        }                                                                        \
        if (fg == 0)                                                             \
            ((float4*)in_mem_base)[((size_t)b * M_ + m0 + w) * 128 + (kc) * 8 + c8] = s; \
    } while (0)

    LOAD_CHUNK(qA, mA, 0);
    #pragma unroll
    for (int it = 0; it < 8; ++it) {
        int kc0 = 2 * it, kc1 = 2 * it + 1;
        LOAD_CHUNK(qB, mB, kc1);           // issue early: consumed after barrier+mfma
        CONV_CHUNK(qA, mA, 0);
        __syncthreads();
        MFMA_FSUM(0, kc0);
        if (it < 7) LOAD_CHUNK(qA, mA, kc0 + 2);
        CONV_CHUNK(qB, mB, 1);
        __syncthreads();
        MFMA_FSUM(1, kc1);
    }

    // masks + max over f (16-lane groups), write att_qm; wave w owns m = m0+w
    {
        int m = m0 + w;
        float cmv = ctx_mask[((size_t)b * M_ + m) * F_ + lr];
        #pragma unroll
        for (int tq = 0; tq < 4; ++tq) {
            #pragma unroll
            for (int rg = 0; rg < 4; ++rg) {
                int q = tq * 16 + lg * 4 + rg;
                float qmv = query_mask[b * Q_ + q];
                float v = acc[tq][rg];
                v = cmv * v - (1.0f - cmv) * INF_F;
                v = qmv * v - (1.0f - qmv) * INF_F;
                #pragma unroll
                for (int sh = 1; sh < 16; sh <<= 1) v = fmaxf(v, __shfl_xor(v, sh, 64));
                if (lr == 0)
                    att_qm[((size_t)b * Q_ + q) * M_ + m] = v;
            }
        }
    }
#undef LOAD_CHUNK
#undef CONV_CHUNK
#undef MFMA_FSUM
}

// f-sum of out_memory -> out_mem_sum. 2 m per block, 16 loads in flight.
__global__ __launch_bounds__(256) void k_out_sum(
    const float* __restrict__ om, float* __restrict__ os)
{
    int bm = blockIdx.x * 2 + (threadIdx.x >> 7);
    int c  = threadIdx.x & 127;
    const float4* src = (const float4*)om + (size_t)bm * F_ * 128 + c;
    float4 a = make_float4(0, 0, 0, 0);
    #pragma unroll
    for (int f = 0; f < F_; ++f) {
        float4 v = src[(size_t)f * 128];
        a.x += v.x; a.y += v.y; a.z += v.z; a.w += v.w;
    }
    ((float4*)os)[(size_t)bm * 128 + c] = a;
}

// K3: softmax over M (in-block) + new_query = query + probs @ out_mem_sum
// 128 thr; 8 q per block; bid&15 = b -> XCD pin so out_mem_sum[b] (1 MB) is L2-local.
__global__ __launch_bounds__(128) void k_new_query(
    const float* __restrict__ att, const float* __restrict__ query,
    const float* __restrict__ out_sum, float* __restrict__ new_q)
{
    __shared__ float P[8][512];    // 16 KB
    int bid = blockIdx.x;
    int b = bid & 15, qc = bid >> 4;      // qc 0..7
    int t = threadIdx.x;
    {
        int qi = t >> 4, l16 = t & 15;
        const float* row = att + ((size_t)b * Q_ + qc * 8 + qi) * M_;
        float vals[32]; float mx = -INF_F;
        #pragma unroll
        for (int i = 0; i < 32; ++i) { vals[i] = row[l16 + i * 16]; mx = fmaxf(mx, vals[i]); }
        #pragma unroll
        for (int s = 1; s < 16; s <<= 1) mx = fmaxf(mx, __shfl_xor(mx, s, 64));
        float sm = 0.f;
        #pragma unroll
        for (int i = 0; i < 32; ++i) { vals[i] = __expf(vals[i] - mx); sm += vals[i]; }
        #pragma unroll
        for (int s = 1; s < 16; s <<= 1) sm += __shfl_xor(sm, s, 64);
        float inv = 1.0f / sm;
        #pragma unroll
        for (int i = 0; i < 32; ++i) P[qi][l16 + i * 16] = vals[i] * inv;
    }
    __syncthreads();
    int c = t;   // float4 col
    const float4* o4 = (const float4*)out_sum + (size_t)b * M_ * 128 + c;
    const float4* q4 = (const float4*)query + ((size_t)b * Q_ + qc * 8) * 128 + c;
    float4 acc[8];
    #pragma unroll
    for (int qi = 0; qi < 8; ++qi) acc[qi] = q4[(size_t)qi * 128];
    for (int mm = 0; mm < M_; mm += 4) {
        float4 o0 = o4[(size_t)(mm + 0) * 128];
        float4 o1 = o4[(size_t)(mm + 1) * 128];
        float4 o2 = o4[(size_t)(mm + 2) * 128];
        float4 o3 = o4[(size_t)(mm + 3) * 128];
        #pragma unroll
        for (int qi = 0; qi < 8; ++qi) {
            float4 p = *(const float4*)&P[qi][mm];
            acc[qi].x += p.x * o0.x + p.y * o1.x + p.z * o2.x + p.w * o3.x;
            acc[qi].y += p.x * o0.y + p.y * o1.y + p.z * o2.y + p.w * o3.y;
            acc[qi].z += p.x * o0.z + p.y * o1.z + p.z * o2.z + p.w * o3.z;
            acc[qi].w += p.x * o0.w + p.y * o1.w + p.z * o2.w + p.w * o3.w;
        }
    }
    float4* n4 = (float4*)new_q + ((size_t)b * Q_ + qc * 8) * 128 + c;
    #pragma unroll
    for (int qi = 0; qi < 8; ++qi) n4[(size_t)qi * 128] = acc[qi];
}

// K4: softmax over Q (in-block) + in_mem += p2 @ new_query
// 128 thr; 8 m per block; bid&15 = b -> XCD pin so new_q[b] (128 KB) is L2-local.
__global__ __launch_bounds__(128) void k_in_mem(
    const float* __restrict__ att, const float* __restrict__ new_q,
    float* __restrict__ in_mem_io)
{
    __shared__ float P[8][64];     // 2 KB
    int bid = blockIdx.x;
    int b = bid & 15, mc = bid >> 4;      // mc 0..63
    int m0 = mc * 8;
    int t = threadIdx.x;
    {
        int mi = t >> 4, l16 = t & 15;
        float v[4]; float mx = -INF_F;
        #pragma unroll
        for (int i = 0; i < 4; ++i) {
            v[i] = att[((size_t)b * Q_ + l16 + i * 16) * M_ + m0 + mi];
            mx = fmaxf(mx, v[i]);
        }
        #pragma unroll
        for (int s = 1; s < 16; s <<= 1) mx = fmaxf(mx, __shfl_xor(mx, s, 64));
        float sm = 0.f;
        #pragma unroll
        for (int i = 0; i < 4; ++i) { v[i] = __expf(v[i] - mx); sm += v[i]; }
        #pragma unroll
        for (int s = 1; s < 16; s <<= 1) sm += __shfl_xor(sm, s, 64);
        float inv = 1.0f / sm;
        #pragma unroll
        for (int i = 0; i < 4; ++i) P[mi][l16 + i * 16] = v[i] * inv;
    }
    __syncthreads();
    int c = t;
    float4* io = (float4*)in_mem_io + ((size_t)b * M_ + m0) * 128 + c;
    const float4* n4 = (const float4*)new_q + (size_t)b * Q_ * 128 + c;
    float4 acc[8];
    #pragma unroll
    for (int mi = 0; mi < 8; ++mi) acc[mi] = io[(size_t)mi * 128];
    for (int q = 0; q < Q_; q += 4) {
        float4 n0 = n4[(size_t)(q + 0) * 128];
        float4 n1 = n4[(size_t)(q + 1) * 128];
        float4 n2 = n4[(size_t)(q + 2) * 128];
        float4 n3 = n4[(size_t)(q + 3) * 128];
        #pragma unroll
        for (int mi = 0; mi < 8; ++mi) {
            float4 p = *(const float4*)&P[mi][q];
            acc[mi].x += p.x * n0.x + p.y * n1.x + p.z * n2.x + p.w * n3.x;
            acc[mi].y += p.x * n0.y + p.y * n1.y + p.z * n2.y + p.w * n3.y;
            acc[mi].z += p.x * n0.z + p.y * n1.z + p.z * n2.z + p.w * n3.z;
            acc[mi].w += p.x * n0.w + p.y * n1.w + p.z * n2.w + p.w * n3.w;
        }
    }
    #pragma unroll
    for (int mi = 0; mi < 8; ++mi) io[(size_t)mi * 128] = acc[mi];
}

extern "C" void kernel_launch(void* const* d_in, const int* in_sizes, int n_in,
                              void* d_out, int out_size, void* d_ws, size_t ws_size,
                              hipStream_t stream)
{
    const float* query      = (const float*)d_in[0];
    const float* in_mem     = (const float*)d_in[1];
    const float* out_mem    = (const float*)d_in[2];
    const float* ctx_mask   = (const float*)d_in[3];
    const float* query_mask = (const float*)d_in[4];

    float* out = (float*)d_out;
    float* new_q      = out;                             // B*Q*D
    float* in_mem_out = out + (size_t)B_*Q_*D_;          // B*M*D
    float* out_mem_o  = in_mem_out + (size_t)B_*M_*D_;   // B*M*D

    float* att_qm = (float*)d_ws;                        // B*Q*M

    hipLaunchKernelGGL(k_att_mfma, dim3((M_/4) * B_), dim3(256), 0, stream,
                       query, in_mem, ctx_mask, query_mask, att_qm, in_mem_out);
    hipLaunchKernelGGL(k_out_sum, dim3(B_*M_/2), dim3(256), 0, stream,
                       out_mem, out_mem_o);
    hipLaunchKernelGGL(k_new_query, dim3(8 * B_), dim3(128), 0, stream,
                       att_qm, query, out_mem_o, new_q);
    hipLaunchKernelGGL(k_in_mem, dim3(64 * B_), dim3(128), 0, stream,
                       att_qm, new_q, in_mem_out);
}